// Round 6
// baseline (236.205 us; speedup 1.0000x reference)
//
#include <hip/hip_runtime.h>
#include <cstdint>
#include <cmath>

#define Bn 4096
#define Dn 256
#define On 256

typedef __bf16 v8bf __attribute__((ext_vector_type(8)));
typedef float  v16f __attribute__((ext_vector_type(16)));
typedef unsigned short us8 __attribute__((ext_vector_type(8)));

__device__ __forceinline__ unsigned short f2bf(float f) {
    // round-to-nearest-even fp32 -> bf16 (inputs are finite normals)
    unsigned int u = __builtin_bit_cast(unsigned int, f);
    unsigned int r = (u + 0x7fffu + ((u >> 16) & 1u)) >> 16;
    return (unsigned short)r;
}

__device__ __forceinline__ void gl_lds16(const void* g, void* l) {
    __builtin_amdgcn_global_load_lds(
        (const __attribute__((address_space(1))) void*)(uintptr_t)g,
        (__attribute__((address_space(3))) void*)(uintptr_t)l, 16, 0, 0);
}

// ---------------------------------------------------------------------------
// Kernel 1: x (fp32, [b][k] row-major) -> xbT (bf16, k-major 16B units:
// unit g = kc*Bn + b holds x[b][kc*8 .. kc*8+8]).  LDS-transpose per block.
// ---------------------------------------------------------------------------
__global__ __launch_bounds__(256) void prep_x(const float* __restrict__ x,
                                              unsigned short* __restrict__ xbT) {
    __shared__ float t[64][68];          // +4 pad: conflict-free col reads
    const int tid = threadIdx.x;
    const int bb = blockIdx.x >> 2;      // 64 b-tiles of 64
    const int kb = blockIdx.x & 3;       // 4 k-quarters of 64
    const int b0 = bb * 64;
#pragma unroll
    for (int s = 0; s < 4; ++s) {
        const int idx = s * 256 + tid;
        const int r = idx >> 4, c4 = idx & 15;
        const float4 v = *(const float4*)(x + (size_t)(b0 + r) * Dn + kb * 64 + c4 * 4);
        *(float4*)&t[r][c4 * 4] = v;
    }
    __syncthreads();
    const int lane = tid & 63, wv = tid >> 6;
#pragma unroll
    for (int s = 0; s < 2; ++s) {
        const int kcl = s * 4 + wv;      // 0..7 local k-chunk
        us8 u;
#pragma unroll
        for (int q = 0; q < 8; ++q) u[q] = f2bf(t[lane][kcl * 8 + q]);
        *(us8*)(xbT + ((size_t)(kb * 8 + kcl) * Bn + b0 + lane) * 8) = u;
    }
}

// ---------------------------------------------------------------------------
// Fragment extraction, 8-wave version: wave wv owns the 32-i strip
// i = wv*32 + (lane&31).  grp = wv>>1 selects which 64-tile the strip is in,
// half = wv&1 which half of the tile.  Tile slot T is [64][64] fp32 with
// row-swizzle (r,c) -> T[r*64 + (c ^ ((r&7)<<2))], pre-swizzled at source.
// af[ks][j] = A[o][i][k = ks*16 + (lane>>5)*8 + j]  (32x32x16 A layout,
// verified on-HW in round 4).
// ---------------------------------------------------------------------------
template <int TI, int TJ>
__device__ __forceinline__ void extract_pair(const float* T, v8bf (&af)[16],
                                             float sc, int wv, int lane) {
    const int l31 = lane & 31, hw = lane >> 5;
    const int half = wv & 1, grp = wv >> 1;
    if (TI == TJ) {
        if (grp == TI) {                 // diagonal tile
            const int r = half * 32 + l31;
            const int mr = (r & 7) << 2;
#pragma unroll
            for (int kq = 0; kq < 4; ++kq) {
                us8 u;
#pragma unroll
                for (int q = 0; q < 8; ++q) {
                    const int c = kq * 16 + hw * 8 + q;
                    const float v = (r < c) ? T[r * 64 + (c ^ mr)]
                                  : ((r > c) ? T[c * 64 + (r ^ ((c & 7) << 2))]
                                             : sc);
                    u[q] = f2bf(v);
                }
                af[TI * 4 + kq] = __builtin_bit_cast(v8bf, u);
            }
        }
    } else {
        if (grp == TI) {                 // row side: i in TI, k-block TJ
            const int r = half * 32 + l31;
            const int mr = (r & 7) << 2;
#pragma unroll
            for (int kq = 0; kq < 4; ++kq) {
                const int c0 = kq * 16 + hw * 8;
                const float4 a = *(const float4*)&T[r * 64 + (c0 ^ mr)];
                const float4 b = *(const float4*)&T[r * 64 + ((c0 + 4) ^ mr)];
                us8 u;
                u[0] = f2bf(a.x); u[1] = f2bf(a.y); u[2] = f2bf(a.z); u[3] = f2bf(a.w);
                u[4] = f2bf(b.x); u[5] = f2bf(b.y); u[6] = f2bf(b.z); u[7] = f2bf(b.w);
                af[TJ * 4 + kq] = __builtin_bit_cast(v8bf, u);
            }
        } else if (grp == TJ) {          // col side: i in TJ, k-block TI
            const int cL = half * 32 + l31;
#pragma unroll
            for (int kq = 0; kq < 4; ++kq) {
                us8 u;
#pragma unroll
                for (int q = 0; q < 8; ++q) {
                    const int rL = kq * 16 + hw * 8 + q;
                    u[q] = f2bf(T[rL * 64 + (cL ^ ((rL & 7) << 2))]);
                }
                af[TI * 4 + kq] = __builtin_bit_cast(v8bf, u);
            }
        }
    }
}

// Inline-asm waits + compile-scheduler fence (rule #18).
#define WAITV(N)                                              \
    do {                                                      \
        asm volatile("s_waitcnt vmcnt(" #N ")" ::: "memory"); \
        __builtin_amdgcn_sched_barrier(0);                    \
    } while (0)
#define LGKM0()                                               \
    do {                                                      \
        asm volatile("s_waitcnt lgkmcnt(0)" ::: "memory");    \
        __builtin_amdgcn_sched_barrier(0);                    \
    } while (0)
#define BARF()                                                \
    do {                                                      \
        __builtin_amdgcn_sched_barrier(0);                    \
        __builtin_amdgcn_s_barrier();                         \
        __builtin_amdgcn_sched_barrier(0);                    \
    } while (0)

// Stage rot tile (TIv,TJv) into slot DST (16 KB) with source pre-swizzle.
// 512 threads -> 2 gl_lds16 per thread (2 vm-instrs per wave).
#define STAGE_T(TIv, TJv, DST)                                               \
    do {                                                                     \
        const float* s_ = rbase + (TIv) * (64 * Dn) + (TJv) * 64;            \
        _Pragma("unroll")                                                    \
        for (int s = 0; s < 2; ++s) {                                        \
            const int idx = s * 512 + tid;                                   \
            const int r = idx >> 4, c4 = idx & 15;                           \
            gl_lds16(s_ + (size_t)r * Dn + ((c4 ^ (r & 7)) * 4),             \
                     (DST) + idx * 4);                                       \
        }                                                                    \
    } while (0)

// ---------------------------------------------------------------------------
// Kernel 2: fused A-build + GEMM + norm + bell, 32x32x16 MFMA, 8-wave
// blocks.  Each wave owns a 32-i strip: af[16] = 64 VGPR, acc[2] = 32 -> fits
// the 128-reg cap of __launch_bounds__(512,4) => 2 blocks/CU = 4 waves/SIMD
// (vs 2 before): dependent-MFMA latency, epilogue VALU and barrier drains
// are now hidden by cross-wave scheduling.  Main-loop math identical to the
// proven round-4 kernel (absmax invariant).
// ---------------------------------------------------------------------------
__global__ __launch_bounds__(512, 4) void fuzzy_main(
    const float* __restrict__ rots, const float* __restrict__ scales,
    const unsigned short* __restrict__ xbT, const float* __restrict__ cent,
    const float* __restrict__ bvals, float* __restrict__ out) {
    __shared__ __align__(16) unsigned short Xs[2][2048][8];  // 64 KB dbuf
    __shared__ float ssbuf[2][8][64];                        // parity dbuf
    __shared__ float centL[Dn];

    const int tid  = threadIdx.x;        // 0..511
    const int lane = tid & 63;
    const int wv   = tid >> 6;           // 0..7: i-strip index
    const int l31  = lane & 31, hw = lane >> 5;
    // grid 512 = 8 xcd x 32 olow x 2 bhalf
    const int Lb = blockIdx.x;
    const int o     = (Lb & 7) * 32 + ((Lb >> 3) & 31);
    const int bhalf = Lb >> 8;
    const int bh0   = bhalf * 2048;

    if (tid < Dn) centL[tid] = cent[o * Dn + tid];
    const float sc = scales[o * Dn + wv * 32 + l31];
    const float bv = bvals[o];

    WAITV(0);   // drain scalar-ish vector loads -> clean vmcnt counting

    // ---- A-build prologue: 4 slots, 2 rounds (4 vm-instr each) in flight ----
    float* const S0 = (float*)&Xs[0][0][0];
    float* const S1 = S0 + 4096;
    float* const S2 = (float*)&Xs[1][0][0];
    float* const S3 = S2 + 4096;
    const float* const rbase = rots + ((size_t)o << 16);

    v8bf af[16];                         // 64 VGPRs

    STAGE_T(0, 1, S0); STAGE_T(2, 3, S1);        // R1 (4 instr/wave)
    STAGE_T(0, 2, S2); STAGE_T(1, 3, S3);        // R2 (8 outstanding)
    WAITV(4); BARF();                            // R1 ready
    extract_pair<0, 1>(S0, af, sc, wv, lane);    // w0,w1 row / w2,w3 col
    extract_pair<2, 3>(S1, af, sc, wv, lane);    // w4,w5 row / w6,w7 col
    LGKM0(); BARF();
    STAGE_T(0, 3, S0); STAGE_T(1, 2, S1);        // R3
    WAITV(4); BARF();                            // R2 ready
    extract_pair<0, 2>(S2, af, sc, wv, lane);
    extract_pair<1, 3>(S3, af, sc, wv, lane);
    LGKM0(); BARF();
    STAGE_T(0, 0, S2); STAGE_T(1, 1, S3);        // R4
    WAITV(4); BARF();                            // R3 ready
    extract_pair<0, 3>(S0, af, sc, wv, lane);
    extract_pair<1, 2>(S1, af, sc, wv, lane);
    LGKM0(); BARF();
    STAGE_T(2, 2, S0); STAGE_T(3, 3, S1);        // R5
    WAITV(4); BARF();                            // R4 ready
    extract_pair<0, 0>(S2, af, sc, wv, lane);    // w0,w1
    extract_pair<1, 1>(S3, af, sc, wv, lane);    // w2,w3
    LGKM0(); BARF();
    WAITV(0); BARF();                            // R5 ready
    extract_pair<2, 2>(S0, af, sc, wv, lane);    // w4,w5
    extract_pair<3, 3>(S1, af, sc, wv, lane);    // w6,w7
    LGKM0(); BARF();

    // ---- X staging pointers (persistent, +64 b-rows per btile) ----
    const unsigned short* px[4];
#pragma unroll
    for (int s = 0; s < 4; ++s)
        px[s] = xbT + ((size_t)(s * 8 + wv) * Bn + bh0 + lane) * 8;

    // stage btile 0 into buffer 0 (4 gl_lds16 per thread)
#pragma unroll
    for (int s = 0; s < 4; ++s)
        gl_lds16(px[s], &Xs[0][s * 512 + tid][0]);
    __syncthreads();                     // drains X staging + syncs

    for (int it = 0; it < 32; ++it) {
        const int buf = it & 1;
        if (it < 31) {                   // prefetch next btile
#pragma unroll
            for (int s = 0; s < 4; ++s) {
                px[s] += 512;            // +64 b (shorts)
                gl_lds16(px[s], &Xs[buf ^ 1][s * 512 + tid][0]);
            }
        }

        // deferred out-write for btile it-1 (parity buf^1; race-free: that
        // parity was written end of it-1, next written end of it+1, with
        // barriers between)
        if (it >= 1 && lane < 8) {
            const int bl = wv * 8 + lane;
            float ssq = 0.f;
#pragma unroll
            for (int w = 0; w < 8; ++w) ssq += ssbuf[buf ^ 1][w][bl];
            out[(size_t)(bh0 + (it - 1) * 64 + bl) * On + o] =
                1.0f / (1.0f + exp2f(bv * log2f(ssq)));
        }

        v16f acc[2];
#pragma unroll
        for (int nt = 0; nt < 2; ++nt)
#pragma unroll
            for (int rg = 0; rg < 16; ++rg) acc[nt][rg] = 0.f;

#pragma unroll
        for (int ks = 0; ks < 16; ++ks) {
            const v8bf xf0 = *(const v8bf*)&Xs[buf][(ks * 2 + hw) * 64 + l31][0];
            const v8bf xf1 = *(const v8bf*)&Xs[buf][(ks * 2 + hw) * 64 + 32 + l31][0];
            acc[0] = __builtin_amdgcn_mfma_f32_32x32x16_bf16(af[ks], xf0, acc[0], 0, 0, 0);
            acc[1] = __builtin_amdgcn_mfma_f32_32x32x16_bf16(af[ks], xf1, acc[1], 0, 0, 0);
        }

        // epilogue: partial sum_i y^2 for this wave's 32 i.  C/D map
        // (measured m74/m101): b = nt*32 + l31, i_loc = (rg&3)+8*(rg>>2)+4*hw.
#pragma unroll
        for (int nt = 0; nt < 2; ++nt) {
            float v = 0.f;
#pragma unroll
            for (int g = 0; g < 4; ++g) {
                const float4 c4 = *(const float4*)&centL[wv * 32 + 8 * g + 4 * hw];
                float y;
                y = acc[nt][g * 4 + 0] + c4.x; v = fmaf(y, y, v);
                y = acc[nt][g * 4 + 1] + c4.y; v = fmaf(y, y, v);
                y = acc[nt][g * 4 + 2] + c4.z; v = fmaf(y, y, v);
                y = acc[nt][g * 4 + 3] + c4.w; v = fmaf(y, y, v);
            }
            v += __shfl_xor(v, 32);
            if (lane < 32) ssbuf[buf][wv][nt * 32 + lane] = v;
        }
        __syncthreads();   // Xs[buf^1] staged (covered by MFMA burst),
                           // ssbuf[buf] visible
    }
    // tail: out-write for btile 31 (parity 1; last loop iter ended in barrier)
    if (lane < 8) {
        const int bl = wv * 8 + lane;
        float ssq = 0.f;
#pragma unroll
        for (int w = 0; w < 8; ++w) ssq += ssbuf[1][w][bl];
        out[(size_t)(bh0 + 31 * 64 + bl) * On + o] =
            1.0f / (1.0f + exp2f(bv * log2f(ssq)));
    }
}

// ---------------------------------------------------------------------------
// Fallback (only if d_ws is too small): exact fp32, slow but correct.
// ---------------------------------------------------------------------------
__global__ void fallback_kernel(const float* __restrict__ x, const float* __restrict__ scales,
                                const float* __restrict__ rots, const float* __restrict__ cent,
                                const float* __restrict__ bvals, float* __restrict__ out) {
    const int b = blockIdx.x * blockDim.x + threadIdx.x;
    const int o = blockIdx.y;
    if (b >= Bn) return;
    const float* R  = rots + (size_t)o * Dn * Dn;
    const float* xv = x + (size_t)b * Dn;
    float ss = 0.f;
    for (int i = 0; i < Dn; ++i) {
        float a = cent[o * Dn + i];
        for (int j = 0; j < Dn; ++j) {
            const float w = (j > i) ? R[i * Dn + j]
                          : ((j < i) ? R[j * Dn + i] : scales[o * Dn + i]);
            a += w * xv[j];
        }
        ss += a * a;
    }
    out[(size_t)b * On + o] = 1.f / (1.f + powf(ss, bvals[o]));
}

extern "C" void kernel_launch(void* const* d_in, const int* in_sizes, int n_in,
                              void* d_out, int out_size, void* d_ws, size_t ws_size,
                              hipStream_t stream) {
    const float* x         = (const float*)d_in[0];
    const float* scales    = (const float*)d_in[1];
    const float* rots      = (const float*)d_in[2];
    const float* centroids = (const float*)d_in[3];
    const float* bvals     = (const float*)d_in[4];
    float* out = (float*)d_out;

    const size_t needX = (size_t)Bn * Dn * sizeof(unsigned short);      // 2.1 MB

    if (ws_size >= needX) {
        unsigned short* xbT = (unsigned short*)d_ws;
        prep_x<<<dim3(256), 256, 0, stream>>>(x, xbT);
        fuzzy_main<<<dim3(512), 512, 0, stream>>>(rots, scales, xbT, centroids, bvals, out);
    } else {
        fallback_kernel<<<dim3(Bn / 256, On), 256, 0, stream>>>(x, scales, rots, centroids,
                                                                bvals, out);
    }
}

// Round 7
// 232.252 us; speedup vs baseline: 1.0170x; 1.0170x over previous
//
#include <hip/hip_runtime.h>
#include <cstdint>
#include <cmath>

#define Bn 4096
#define Dn 256
#define On 256

typedef __bf16 v8bf __attribute__((ext_vector_type(8)));
typedef float  v16f __attribute__((ext_vector_type(16)));
typedef unsigned short us8 __attribute__((ext_vector_type(8)));

__device__ __forceinline__ unsigned short f2bf(float f) {
    // round-to-nearest-even fp32 -> bf16 (inputs are finite normals)
    unsigned int u = __builtin_bit_cast(unsigned int, f);
    unsigned int r = (u + 0x7fffu + ((u >> 16) & 1u)) >> 16;
    return (unsigned short)r;
}

__device__ __forceinline__ void gl_lds16(const void* g, void* l) {
    __builtin_amdgcn_global_load_lds(
        (const __attribute__((address_space(1))) void*)(uintptr_t)g,
        (__attribute__((address_space(3))) void*)(uintptr_t)l, 16, 0, 0);
}

// ---------------------------------------------------------------------------
// Kernel 1: x (fp32, [b][k] row-major) -> xbT (bf16, k-major 16B units:
// unit g = kc*Bn + b holds x[b][kc*8 .. kc*8+8]).  LDS-transpose per block.
// ---------------------------------------------------------------------------
__global__ __launch_bounds__(256) void prep_x(const float* __restrict__ x,
                                              unsigned short* __restrict__ xbT) {
    __shared__ float t[64][68];          // +4 pad: conflict-free col reads
    const int tid = threadIdx.x;
    const int bb = blockIdx.x >> 2;      // 64 b-tiles of 64
    const int kb = blockIdx.x & 3;       // 4 k-quarters of 64
    const int b0 = bb * 64;
#pragma unroll
    for (int s = 0; s < 4; ++s) {
        const int idx = s * 256 + tid;
        const int r = idx >> 4, c4 = idx & 15;
        const float4 v = *(const float4*)(x + (size_t)(b0 + r) * Dn + kb * 64 + c4 * 4);
        *(float4*)&t[r][c4 * 4] = v;
    }
    __syncthreads();
    const int lane = tid & 63, wv = tid >> 6;
#pragma unroll
    for (int s = 0; s < 2; ++s) {
        const int kcl = s * 4 + wv;      // 0..7 local k-chunk
        us8 u;
#pragma unroll
        for (int q = 0; q < 8; ++q) u[q] = f2bf(t[lane][kcl * 8 + q]);
        *(us8*)(xbT + ((size_t)(kb * 8 + kcl) * Bn + b0 + lane) * 8) = u;
    }
}

// ---------------------------------------------------------------------------
// Fragment extraction, 8-wave version (VERBATIM from the round-6 proven
// kernel): wave wv owns the 32-i strip i = wv*32 + (lane&31).  grp = wv>>1,
// half = wv&1.  Tile slot T is [64][64] fp32 with row-swizzle
// (r,c) -> T[r*64 + (c ^ ((r&7)<<2))], pre-swizzled at the global source.
// af[ks][j] = A[o][i][k = ks*16 + (lane>>5)*8 + j]  (32x32x16 A layout).
// ---------------------------------------------------------------------------
template <int TI, int TJ>
__device__ __forceinline__ void extract_pair(const float* T, v8bf (&af)[16],
                                             float sc, int wv, int lane) {
    const int l31 = lane & 31, hw = lane >> 5;
    const int half = wv & 1, grp = wv >> 1;
    if (TI == TJ) {
        if (grp == TI) {                 // diagonal tile
            const int r = half * 32 + l31;
            const int mr = (r & 7) << 2;
#pragma unroll
            for (int kq = 0; kq < 4; ++kq) {
                us8 u;
#pragma unroll
                for (int q = 0; q < 8; ++q) {
                    const int c = kq * 16 + hw * 8 + q;
                    const float v = (r < c) ? T[r * 64 + (c ^ mr)]
                                  : ((r > c) ? T[c * 64 + (r ^ ((c & 7) << 2))]
                                             : sc);
                    u[q] = f2bf(v);
                }
                af[TI * 4 + kq] = __builtin_bit_cast(v8bf, u);
            }
        }
    } else {
        if (grp == TI) {                 // row side: i in TI, k-block TJ
            const int r = half * 32 + l31;
            const int mr = (r & 7) << 2;
#pragma unroll
            for (int kq = 0; kq < 4; ++kq) {
                const int c0 = kq * 16 + hw * 8;
                const float4 a = *(const float4*)&T[r * 64 + (c0 ^ mr)];
                const float4 b = *(const float4*)&T[r * 64 + ((c0 + 4) ^ mr)];
                us8 u;
                u[0] = f2bf(a.x); u[1] = f2bf(a.y); u[2] = f2bf(a.z); u[3] = f2bf(a.w);
                u[4] = f2bf(b.x); u[5] = f2bf(b.y); u[6] = f2bf(b.z); u[7] = f2bf(b.w);
                af[TJ * 4 + kq] = __builtin_bit_cast(v8bf, u);
            }
        } else if (grp == TJ) {          // col side: i in TJ, k-block TI
            const int cL = half * 32 + l31;
#pragma unroll
            for (int kq = 0; kq < 4; ++kq) {
                us8 u;
#pragma unroll
                for (int q = 0; q < 8; ++q) {
                    const int rL = kq * 16 + hw * 8 + q;
                    u[q] = f2bf(T[rL * 64 + (cL ^ ((rL & 7) << 2))]);
                }
                af[TI * 4 + kq] = __builtin_bit_cast(v8bf, u);
            }
        }
    }
}

// Inline-asm waits + compile-scheduler fence (rule #18).
#define WAITV(N)                                              \
    do {                                                      \
        asm volatile("s_waitcnt vmcnt(" #N ")" ::: "memory"); \
        __builtin_amdgcn_sched_barrier(0);                    \
    } while (0)
#define LGKM0()                                               \
    do {                                                      \
        asm volatile("s_waitcnt lgkmcnt(0)" ::: "memory");    \
        __builtin_amdgcn_sched_barrier(0);                    \
    } while (0)
#define BARF()                                                \
    do {                                                      \
        __builtin_amdgcn_sched_barrier(0);                    \
        __builtin_amdgcn_s_barrier();                         \
        __builtin_amdgcn_sched_barrier(0);                    \
    } while (0)

// Stage rot tile (TIv,TJv) into slot DST (16 KB) with source pre-swizzle.
// 512 threads -> 2 gl_lds16 per thread (2 vm-instrs per wave).
#define STAGE_T(TIv, TJv, DST)                                               \
    do {                                                                     \
        const float* s_ = rbase + (TIv) * (64 * Dn) + (TJv) * 64;            \
        _Pragma("unroll")                                                    \
        for (int s = 0; s < 2; ++s) {                                        \
            const int idx = s * 512 + tid;                                   \
            const int r = idx >> 4, c4 = idx & 15;                           \
            gl_lds16(s_ + (size_t)r * Dn + ((c4 ^ (r & 7)) * 4),             \
                     (DST) + idx * 4);                                       \
        }                                                                    \
    } while (0)

// Stage one 32-b X btile into buffer BUF (2 gl_lds16/thread); px auto-advances.
#define STAGE_X(BUF)                                                         \
    do {                                                                     \
        _Pragma("unroll")                                                    \
        for (int s = 0; s < 2; ++s) {                                        \
            gl_lds16(px[s], &Xs[BUF][s * 512 + tid][0]);                     \
            px[s] += 256;  /* next btile: +32 b * 8 shorts */                \
        }                                                                    \
    } while (0)

// ---------------------------------------------------------------------------
// Kernel 2: fused A-build + GEMM + norm + bell.  T3+T4+T5 main loop:
// 64 btiles of 32 b through 4 rotating 16 KB LDS buffers, prefetch depth 3,
// counted vmcnt(4) (never 0 until tail) so loads stay in flight ACROSS the
// per-iter barrier; raw lgkmcnt(0)+s_barrier; s_setprio(1) around the MFMA
// burst.  Each wave: 32-i strip (af[16]=64 VGPR), full 32-b btile, 16 MFMA
// in 2 ks-parity chains (8 chains/SIMD at 4 waves/SIMD).  vmcnt ledger:
// steady iter t enters with {t+1,t+2} staged-or-inflight (4), issues t+3
// (6), end-of-iter WAITV(4) drains t+1; tail t=61/62 step down 2/0.
// ---------------------------------------------------------------------------
__global__ __launch_bounds__(512, 4) void fuzzy_main(
    const float* __restrict__ rots, const float* __restrict__ scales,
    const unsigned short* __restrict__ xbT, const float* __restrict__ cent,
    const float* __restrict__ bvals, float* __restrict__ out) {
    __shared__ __align__(16) unsigned short Xs[4][1024][8];  // 4 x 16 KB
    __shared__ float ssbuf[2][8][32];                        // parity dbuf
    __shared__ float centL[Dn];

    const int tid  = threadIdx.x;        // 0..511
    const int lane = tid & 63;
    const int wv   = tid >> 6;           // 0..7: i-strip index
    const int l31  = lane & 31, hw = lane >> 5;
    // grid 512 = 8 xcd x 32 olow x 2 bhalf
    const int Lb = blockIdx.x;
    const int o     = (Lb & 7) * 32 + ((Lb >> 3) & 31);
    const int bhalf = Lb >> 8;
    const int bh0   = bhalf * 2048;

    if (tid < Dn) centL[tid] = cent[o * Dn + tid];
    const float sc = scales[o * Dn + wv * 32 + l31];
    const float bv = bvals[o];

    WAITV(0);   // drain the scalar-ish vector loads -> clean vmcnt counting

    // ---- A-build prologue (VERBATIM round-6 schedule, proven) ----
    float* const S0 = (float*)&Xs[0][0][0];
    float* const S1 = (float*)&Xs[1][0][0];
    float* const S2 = (float*)&Xs[2][0][0];
    float* const S3 = (float*)&Xs[3][0][0];
    const float* const rbase = rots + ((size_t)o << 16);

    v8bf af[16];                         // 64 VGPRs

    STAGE_T(0, 1, S0); STAGE_T(2, 3, S1);        // R1 (4 instr/wave)
    STAGE_T(0, 2, S2); STAGE_T(1, 3, S3);        // R2 (8 outstanding)
    WAITV(4); BARF();                            // R1 ready
    extract_pair<0, 1>(S0, af, sc, wv, lane);
    extract_pair<2, 3>(S1, af, sc, wv, lane);
    LGKM0(); BARF();
    STAGE_T(0, 3, S0); STAGE_T(1, 2, S1);        // R3
    WAITV(4); BARF();                            // R2 ready
    extract_pair<0, 2>(S2, af, sc, wv, lane);
    extract_pair<1, 3>(S3, af, sc, wv, lane);
    LGKM0(); BARF();
    STAGE_T(0, 0, S2); STAGE_T(1, 1, S3);        // R4
    WAITV(4); BARF();                            // R3 ready
    extract_pair<0, 3>(S0, af, sc, wv, lane);
    extract_pair<1, 2>(S1, af, sc, wv, lane);
    LGKM0(); BARF();
    STAGE_T(2, 2, S0); STAGE_T(3, 3, S1);        // R5
    WAITV(4); BARF();                            // R4 ready
    extract_pair<0, 0>(S2, af, sc, wv, lane);
    extract_pair<1, 1>(S3, af, sc, wv, lane);
    LGKM0(); BARF();
    WAITV(0); BARF();                            // R5 ready
    extract_pair<2, 2>(S0, af, sc, wv, lane);
    extract_pair<3, 3>(S1, af, sc, wv, lane);
    LGKM0(); BARF();                             // all extracts drained

    // ---- X staging pointers: unit (kc local, b local) of the next btile ----
    const unsigned short* px[2];
#pragma unroll
    for (int s = 0; s < 2; ++s) {
        const int idx = s * 512 + tid;
        px[s] = xbT + ((size_t)(idx >> 5) * Bn + bh0 + (idx & 31)) * 8;
    }

    // prime the pipeline: btiles 0,1,2 into buffers 0,1,2
    STAGE_X(0); STAGE_X(1); STAGE_X(2);
    WAITV(4);   // btile 0 drained; {1,2} stay in flight
    LGKM0(); BARF();

    for (int t = 0; t < 64; ++t) {
        const int buf = t & 3;
        if (t <= 60) STAGE_X((t + 3) & 3);   // depth-3 prefetch

        // deferred out-write for btile t-1 (ssbuf parity (t-1)&1, made
        // visible by last iter's lgkm-drain + barrier; its next writer is
        // EPI(t+1) after this iter's barrier -> race-free)
        if (t >= 1 && lane < 4) {
            const int bl = wv * 4 + lane;
            float ssq = 0.f;
#pragma unroll
            for (int w = 0; w < 8; ++w) ssq += ssbuf[(t - 1) & 1][w][bl];
            out[(size_t)(bh0 + (t - 1) * 32 + bl) * On + o] =
                1.0f / (1.0f + exp2f(bv * log2f(ssq)));
        }

        // ---- MFMA burst: 16 ks, 2 ks-parity chains, setprio-boosted ----
        v16f a0, a1;
#pragma unroll
        for (int rg = 0; rg < 16; ++rg) { a0[rg] = 0.f; a1[rg] = 0.f; }
        __builtin_amdgcn_s_setprio(1);
#pragma unroll
        for (int ks = 0; ks < 16; ++ks) {
            const v8bf xf = *(const v8bf*)&Xs[buf][(ks * 2 + hw) * 32 + l31][0];
            if (ks & 1)
                a1 = __builtin_amdgcn_mfma_f32_32x32x16_bf16(af[ks], xf, a1, 0, 0, 0);
            else
                a0 = __builtin_amdgcn_mfma_f32_32x32x16_bf16(af[ks], xf, a0, 0, 0, 0);
        }
        __builtin_amdgcn_s_setprio(0);

        // ---- epilogue: sum_i y^2 over this wave's 32 i.  C/D map
        // (measured m74/m101): b = l31, i_loc = (rg&3)+8*(rg>>2)+4*hw.
        {
            float v = 0.f;
#pragma unroll
            for (int g = 0; g < 4; ++g) {
                const float4 c4 = *(const float4*)&centL[wv * 32 + 8 * g + 4 * hw];
                float y;
                y = a0[g * 4 + 0] + a1[g * 4 + 0] + c4.x; v = fmaf(y, y, v);
                y = a0[g * 4 + 1] + a1[g * 4 + 1] + c4.y; v = fmaf(y, y, v);
                y = a0[g * 4 + 2] + a1[g * 4 + 2] + c4.z; v = fmaf(y, y, v);
                y = a0[g * 4 + 3] + a1[g * 4 + 3] + c4.w; v = fmaf(y, y, v);
            }
            v += __shfl_xor(v, 32);
            if (lane < 32) ssbuf[t & 1][wv][l31] = v;
        }

        // ---- counted sync: next btile staged, LDS ops drained, barrier ----
        if (t < 61)      WAITV(4);
        else if (t == 61) WAITV(2);
        else              WAITV(0);
        LGKM0(); BARF();
    }

    // tail: out-write for btile 63 (parity 1; barrier above makes it visible)
    if (lane < 4) {
        const int bl = wv * 4 + lane;
        float ssq = 0.f;
#pragma unroll
        for (int w = 0; w < 8; ++w) ssq += ssbuf[1][w][bl];
        out[(size_t)(bh0 + 63 * 32 + bl) * On + o] =
            1.0f / (1.0f + exp2f(bv * log2f(ssq)));
    }
}

// ---------------------------------------------------------------------------
// Fallback (only if d_ws is too small): exact fp32, slow but correct.
// ---------------------------------------------------------------------------
__global__ void fallback_kernel(const float* __restrict__ x, const float* __restrict__ scales,
                                const float* __restrict__ rots, const float* __restrict__ cent,
                                const float* __restrict__ bvals, float* __restrict__ out) {
    const int b = blockIdx.x * blockDim.x + threadIdx.x;
    const int o = blockIdx.y;
    if (b >= Bn) return;
    const float* R  = rots + (size_t)o * Dn * Dn;
    const float* xv = x + (size_t)b * Dn;
    float ss = 0.f;
    for (int i = 0; i < Dn; ++i) {
        float a = cent[o * Dn + i];
        for (int j = 0; j < Dn; ++j) {
            const float w = (j > i) ? R[i * Dn + j]
                          : ((j < i) ? R[j * Dn + i] : scales[o * Dn + i]);
            a += w * xv[j];
        }
        ss += a * a;
    }
    out[(size_t)b * On + o] = 1.f / (1.f + powf(ss, bvals[o]));
}

extern "C" void kernel_launch(void* const* d_in, const int* in_sizes, int n_in,
                              void* d_out, int out_size, void* d_ws, size_t ws_size,
                              hipStream_t stream) {
    const float* x         = (const float*)d_in[0];
    const float* scales    = (const float*)d_in[1];
    const float* rots      = (const float*)d_in[2];
    const float* centroids = (const float*)d_in[3];
    const float* bvals     = (const float*)d_in[4];
    float* out = (float*)d_out;

    const size_t needX = (size_t)Bn * Dn * sizeof(unsigned short);      // 2.1 MB

    if (ws_size >= needX) {
        unsigned short* xbT = (unsigned short*)d_ws;
        prep_x<<<dim3(256), 256, 0, stream>>>(x, xbT);
        fuzzy_main<<<dim3(512), 512, 0, stream>>>(rots, scales, xbT, centroids, bvals, out);
    } else {
        fallback_kernel<<<dim3(Bn / 256, On), 256, 0, stream>>>(x, scales, rots, centroids,
                                                                bvals, out);
    }
}

// Round 8
// 226.817 us; speedup vs baseline: 1.0414x; 1.0240x over previous
//
#include <hip/hip_runtime.h>
#include <cstdint>
#include <cmath>

#define Bn 4096
#define Dn 256
#define On 256

typedef __bf16 v8bf __attribute__((ext_vector_type(8)));
typedef float  v16f __attribute__((ext_vector_type(16)));
typedef unsigned short us8 __attribute__((ext_vector_type(8)));

__device__ __forceinline__ unsigned short f2bf(float f) {
    // round-to-nearest-even fp32 -> bf16 (inputs are finite normals)
    unsigned int u = __builtin_bit_cast(unsigned int, f);
    unsigned int r = (u + 0x7fffu + ((u >> 16) & 1u)) >> 16;
    return (unsigned short)r;
}

__device__ __forceinline__ void gl_lds16(const void* g, void* l) {
    __builtin_amdgcn_global_load_lds(
        (const __attribute__((address_space(1))) void*)(uintptr_t)g,
        (__attribute__((address_space(3))) void*)(uintptr_t)l, 16, 0, 0);
}

// ---------------------------------------------------------------------------
// Kernel 1: x (fp32, [b][k] row-major) -> xbT (bf16, k-major 16B units:
// unit g = kc*Bn + b holds x[b][kc*8 .. kc*8+8]).  LDS-transpose per block.
// ---------------------------------------------------------------------------
__global__ __launch_bounds__(256) void prep_x(const float* __restrict__ x,
                                              unsigned short* __restrict__ xbT) {
    __shared__ float t[64][68];          // +4 pad: conflict-free col reads
    const int tid = threadIdx.x;
    const int bb = blockIdx.x >> 2;      // 64 b-tiles of 64
    const int kb = blockIdx.x & 3;       // 4 k-quarters of 64
    const int b0 = bb * 64;
#pragma unroll
    for (int s = 0; s < 4; ++s) {
        const int idx = s * 256 + tid;
        const int r = idx >> 4, c4 = idx & 15;
        const float4 v = *(const float4*)(x + (size_t)(b0 + r) * Dn + kb * 64 + c4 * 4);
        *(float4*)&t[r][c4 * 4] = v;
    }
    __syncthreads();
    const int lane = tid & 63, wv = tid >> 6;
#pragma unroll
    for (int s = 0; s < 2; ++s) {
        const int kcl = s * 4 + wv;      // 0..7 local k-chunk
        us8 u;
#pragma unroll
        for (int q = 0; q < 8; ++q) u[q] = f2bf(t[lane][kcl * 8 + q]);
        *(us8*)(xbT + ((size_t)(kb * 8 + kcl) * Bn + b0 + lane) * 8) = u;
    }
}

// ---------------------------------------------------------------------------
// Fragment extraction, 8-wave version (VERBATIM from the round-6/7 proven
// kernels): wave wv owns the 32-i strip i = wv*32 + (lane&31).  grp = wv>>1,
// half = wv&1.  Tile slot T is [64][64] fp32 with row-swizzle
// (r,c) -> T[r*64 + (c ^ ((r&7)<<2))], pre-swizzled at the global source.
// af[ks][j] = A[o][i][k = ks*16 + (lane>>5)*8 + j]  (32x32x16 A layout).
// ---------------------------------------------------------------------------
template <int TI, int TJ>
__device__ __forceinline__ void extract_pair(const float* T, v8bf (&af)[16],
                                             float sc, int wv, int lane) {
    const int l31 = lane & 31, hw = lane >> 5;
    const int half = wv & 1, grp = wv >> 1;
    if (TI == TJ) {
        if (grp == TI) {                 // diagonal tile
            const int r = half * 32 + l31;
            const int mr = (r & 7) << 2;
#pragma unroll
            for (int kq = 0; kq < 4; ++kq) {
                us8 u;
#pragma unroll
                for (int q = 0; q < 8; ++q) {
                    const int c = kq * 16 + hw * 8 + q;
                    const float v = (r < c) ? T[r * 64 + (c ^ mr)]
                                  : ((r > c) ? T[c * 64 + (r ^ ((c & 7) << 2))]
                                             : sc);
                    u[q] = f2bf(v);
                }
                af[TI * 4 + kq] = __builtin_bit_cast(v8bf, u);
            }
        }
    } else {
        if (grp == TI) {                 // row side: i in TI, k-block TJ
            const int r = half * 32 + l31;
            const int mr = (r & 7) << 2;
#pragma unroll
            for (int kq = 0; kq < 4; ++kq) {
                const int c0 = kq * 16 + hw * 8;
                const float4 a = *(const float4*)&T[r * 64 + (c0 ^ mr)];
                const float4 b = *(const float4*)&T[r * 64 + ((c0 + 4) ^ mr)];
                us8 u;
                u[0] = f2bf(a.x); u[1] = f2bf(a.y); u[2] = f2bf(a.z); u[3] = f2bf(a.w);
                u[4] = f2bf(b.x); u[5] = f2bf(b.y); u[6] = f2bf(b.z); u[7] = f2bf(b.w);
                af[TJ * 4 + kq] = __builtin_bit_cast(v8bf, u);
            }
        } else if (grp == TJ) {          // col side: i in TJ, k-block TI
            const int cL = half * 32 + l31;
#pragma unroll
            for (int kq = 0; kq < 4; ++kq) {
                us8 u;
#pragma unroll
                for (int q = 0; q < 8; ++q) {
                    const int rL = kq * 16 + hw * 8 + q;
                    u[q] = f2bf(T[rL * 64 + (cL ^ ((rL & 7) << 2))]);
                }
                af[TI * 4 + kq] = __builtin_bit_cast(v8bf, u);
            }
        }
    }
}

// Inline-asm waits + compile-scheduler fence (rule #18).
#define WAITV(N)                                              \
    do {                                                      \
        asm volatile("s_waitcnt vmcnt(" #N ")" ::: "memory"); \
        __builtin_amdgcn_sched_barrier(0);                    \
    } while (0)
#define LGKM0()                                               \
    do {                                                      \
        asm volatile("s_waitcnt lgkmcnt(0)" ::: "memory");    \
        __builtin_amdgcn_sched_barrier(0);                    \
    } while (0)
#define BARF()                                                \
    do {                                                      \
        __builtin_amdgcn_sched_barrier(0);                    \
        __builtin_amdgcn_s_barrier();                         \
        __builtin_amdgcn_sched_barrier(0);                    \
    } while (0)

// Stage rot tile (TIv,TJv) into slot DST (16 KB) with source pre-swizzle.
// 512 threads -> 2 gl_lds16 per thread (2 vm-instrs per wave).
#define STAGE_T(TIv, TJv, DST)                                               \
    do {                                                                     \
        const float* s_ = rbase + (TIv) * (64 * Dn) + (TJv) * 64;            \
        _Pragma("unroll")                                                    \
        for (int s = 0; s < 2; ++s) {                                        \
            const int idx = s * 512 + tid;                                   \
            const int r = idx >> 4, c4 = idx & 15;                           \
            gl_lds16(s_ + (size_t)r * Dn + ((c4 ^ (r & 7)) * 4),             \
                     (DST) + idx * 4);                                       \
        }                                                                    \
    } while (0)

// Stage one 32-b X btile into buffer BUF (2 gl_lds16/thread); px auto-advances.
#define STAGE_X(BUF)                                                         \
    do {                                                                     \
        _Pragma("unroll")                                                    \
        for (int s = 0; s < 2; ++s) {                                        \
            gl_lds16(px[s], &Xs[BUF][s * 512 + tid][0]);                     \
            px[s] += 256;  /* next btile: +32 b * 8 shorts */                \
        }                                                                    \
    } while (0)

// ---------------------------------------------------------------------------
// Kernel 2: fused A-build + GEMM + norm + bell.  PAIR-schedule main loop:
// one barrier per 2 btiles (waves drift inside the pair -> one wave's
// epilogue VALU overlaps another's MFMA chain).  Per pair p: stage btiles
// {2p+2,2p+3} at pair start (into the 2 bufs not being read this pair;
// their prior readers drained at last pair's end barrier), compute btiles
// {2p,2p+1} (16-MFMA single chain each, setprio-wrapped), write per-btile
// ssq partials to ssbuf (no bell, no out-write), then vmcnt(0)+lgkm+barrier
// (the stages have had a whole pair to land -> no stall).  Every 4th pair,
// flush the completed 8-btile group: wave w reduces+bells+writes btile
// 8q+w's 32 outputs (amortizes the transcendentals 8x).
// LDS: Xs 64K + ssbuf 8K + centL 1K = 73K -> 2 blocks/CU; regs ~120 -> 4
// waves/SIMD.
// ---------------------------------------------------------------------------
__global__ __launch_bounds__(512, 4) void fuzzy_main(
    const float* __restrict__ rots, const float* __restrict__ scales,
    const unsigned short* __restrict__ xbT, const float* __restrict__ cent,
    const float* __restrict__ bvals, float* __restrict__ out) {
    __shared__ __align__(16) unsigned short Xs[4][1024][8];  // 4 x 16 KB
    __shared__ float ssbuf[8][8][32];    // [btile&7][wave][b-local]  8 KB
    __shared__ float centL[Dn];

    const int tid  = threadIdx.x;        // 0..511
    const int lane = tid & 63;
    const int wv   = tid >> 6;           // 0..7: i-strip index
    const int l31  = lane & 31, hw = lane >> 5;
    // grid 512 = 8 xcd x 32 olow x 2 bhalf
    const int Lb = blockIdx.x;
    const int o     = (Lb & 7) * 32 + ((Lb >> 3) & 31);
    const int bhalf = Lb >> 8;
    const int bh0   = bhalf * 2048;

    if (tid < Dn) centL[tid] = cent[o * Dn + tid];
    const float sc = scales[o * Dn + wv * 32 + l31];
    const float bv = bvals[o];

    WAITV(0);   // drain the scalar-ish vector loads -> clean vmcnt counting

    // ---- A-build prologue (VERBATIM round-6/7 schedule, proven) ----
    float* const S0 = (float*)&Xs[0][0][0];
    float* const S1 = (float*)&Xs[1][0][0];
    float* const S2 = (float*)&Xs[2][0][0];
    float* const S3 = (float*)&Xs[3][0][0];
    const float* const rbase = rots + ((size_t)o << 16);

    v8bf af[16];                         // 64 VGPRs

    STAGE_T(0, 1, S0); STAGE_T(2, 3, S1);        // R1 (4 instr/wave)
    STAGE_T(0, 2, S2); STAGE_T(1, 3, S3);        // R2 (8 outstanding)
    WAITV(4); BARF();                            // R1 ready
    extract_pair<0, 1>(S0, af, sc, wv, lane);
    extract_pair<2, 3>(S1, af, sc, wv, lane);
    LGKM0(); BARF();
    STAGE_T(0, 3, S0); STAGE_T(1, 2, S1);        // R3
    WAITV(4); BARF();                            // R2 ready
    extract_pair<0, 2>(S2, af, sc, wv, lane);
    extract_pair<1, 3>(S3, af, sc, wv, lane);
    LGKM0(); BARF();
    STAGE_T(0, 0, S2); STAGE_T(1, 1, S3);        // R4
    WAITV(4); BARF();                            // R3 ready
    extract_pair<0, 3>(S0, af, sc, wv, lane);
    extract_pair<1, 2>(S1, af, sc, wv, lane);
    LGKM0(); BARF();
    STAGE_T(2, 2, S0); STAGE_T(3, 3, S1);        // R5
    WAITV(4); BARF();                            // R4 ready
    extract_pair<0, 0>(S2, af, sc, wv, lane);
    extract_pair<1, 1>(S3, af, sc, wv, lane);
    LGKM0(); BARF();
    WAITV(0); BARF();                            // R5 ready
    extract_pair<2, 2>(S0, af, sc, wv, lane);
    extract_pair<3, 3>(S1, af, sc, wv, lane);
    LGKM0(); BARF();                             // all extracts drained

    // ---- X staging pointers: unit (kc local, b local) ----
    const unsigned short* px[2];
#pragma unroll
    for (int s = 0; s < 2; ++s) {
        const int idx = s * 512 + tid;
        px[s] = xbT + ((size_t)(idx >> 5) * Bn + bh0 + (idx & 31)) * 8;
    }

    // prime: btiles 0,1 -> bufs 0,1
    STAGE_X(0); STAGE_X(1);
    WAITV(0); LGKM0(); BARF();

    for (int p = 0; p < 32; ++p) {
        const int t0 = 2 * p;
        // stage next pair into the two bufs NOT read this pair (their
        // previous readers were drained at the last pair-end barrier)
        if (p < 31) { STAGE_X((t0 + 2) & 3); STAGE_X((t0 + 3) & 3); }

#pragma unroll
        for (int s = 0; s < 2; ++s) {
            const int t = t0 + s;
            const int buf = t & 3;

            v16f a;
#pragma unroll
            for (int rg = 0; rg < 16; ++rg) a[rg] = 0.f;
            __builtin_amdgcn_s_setprio(1);
#pragma unroll
            for (int ks = 0; ks < 16; ++ks) {
                const v8bf xf = *(const v8bf*)&Xs[buf][(ks * 2 + hw) * 32 + l31][0];
                a = __builtin_amdgcn_mfma_f32_32x32x16_bf16(af[ks], xf, a, 0, 0, 0);
            }
            __builtin_amdgcn_s_setprio(0);

            // partial sum_i y^2 over this wave's 32 i.  C/D map (measured
            // m74/m101): b = l31, i_loc = (rg&3)+8*(rg>>2)+4*hw.
            float v = 0.f;
#pragma unroll
            for (int g = 0; g < 4; ++g) {
                const float4 c4 = *(const float4*)&centL[wv * 32 + 8 * g + 4 * hw];
                float y;
                y = a[g * 4 + 0] + c4.x; v = fmaf(y, y, v);
                y = a[g * 4 + 1] + c4.y; v = fmaf(y, y, v);
                y = a[g * 4 + 2] + c4.z; v = fmaf(y, y, v);
                y = a[g * 4 + 3] + c4.w; v = fmaf(y, y, v);
            }
            v += __shfl_xor(v, 32);
            if (lane < 32) ssbuf[t & 7][wv][l31] = v;
        }

        // pair end: stages landed (issued a whole pair ago), LDS drained
        WAITV(0); LGKM0(); BARF();

        // group flush every 4 pairs: btiles 8q..8q+7 complete & visible.
        // Wave wv owns btile 8q+wv (slot wv); lanes 0-31 reduce 8 partials,
        // bell, strided out-write.  Barrier after protects the slots from
        // next pair's writes.
        if ((p & 3) == 3) {
            const int tb = (p >> 2) * 8 + wv;
            if (lane < 32) {
                float ssq = 0.f;
#pragma unroll
                for (int w2 = 0; w2 < 8; ++w2) ssq += ssbuf[wv][w2][l31];
                out[(size_t)(bh0 + tb * 32 + l31) * On + o] =
                    1.0f / (1.0f + exp2f(bv * log2f(ssq)));
            }
            LGKM0(); BARF();
        }
    }
}

// ---------------------------------------------------------------------------
// Fallback (only if d_ws is too small): exact fp32, slow but correct.
// ---------------------------------------------------------------------------
__global__ void fallback_kernel(const float* __restrict__ x, const float* __restrict__ scales,
                                const float* __restrict__ rots, const float* __restrict__ cent,
                                const float* __restrict__ bvals, float* __restrict__ out) {
    const int b = blockIdx.x * blockDim.x + threadIdx.x;
    const int o = blockIdx.y;
    if (b >= Bn) return;
    const float* R  = rots + (size_t)o * Dn * Dn;
    const float* xv = x + (size_t)b * Dn;
    float ss = 0.f;
    for (int i = 0; i < Dn; ++i) {
        float a = cent[o * Dn + i];
        for (int j = 0; j < Dn; ++j) {
            const float w = (j > i) ? R[i * Dn + j]
                          : ((j < i) ? R[j * Dn + i] : scales[o * Dn + i]);
            a += w * xv[j];
        }
        ss += a * a;
    }
    out[(size_t)b * On + o] = 1.f / (1.f + powf(ss, bvals[o]));
}

extern "C" void kernel_launch(void* const* d_in, const int* in_sizes, int n_in,
                              void* d_out, int out_size, void* d_ws, size_t ws_size,
                              hipStream_t stream) {
    const float* x         = (const float*)d_in[0];
    const float* scales    = (const float*)d_in[1];
    const float* rots      = (const float*)d_in[2];
    const float* centroids = (const float*)d_in[3];
    const float* bvals     = (const float*)d_in[4];
    float* out = (float*)d_out;

    const size_t needX = (size_t)Bn * Dn * sizeof(unsigned short);      // 2.1 MB

    if (ws_size >= needX) {
        unsigned short* xbT = (unsigned short*)d_ws;
        prep_x<<<dim3(256), 256, 0, stream>>>(x, xbT);
        fuzzy_main<<<dim3(512), 512, 0, stream>>>(rots, scales, xbT, centroids, bvals, out);
    } else {
        fallback_kernel<<<dim3(Bn / 256, On), 256, 0, stream>>>(x, scales, rots, centroids,
                                                                bvals, out);
    }
}

// Round 9
// 219.631 us; speedup vs baseline: 1.0755x; 1.0327x over previous
//
#include <hip/hip_runtime.h>
#include <cstdint>
#include <cmath>

#define Bn 4096
#define Dn 256
#define On 256

typedef __bf16 v8bf __attribute__((ext_vector_type(8)));
typedef float  v16f __attribute__((ext_vector_type(16)));
typedef unsigned short us8 __attribute__((ext_vector_type(8)));

__device__ __forceinline__ unsigned short f2bf(float f) {
    // round-to-nearest-even fp32 -> bf16 (inputs are finite normals)
    unsigned int u = __builtin_bit_cast(unsigned int, f);
    unsigned int r = (u + 0x7fffu + ((u >> 16) & 1u)) >> 16;
    return (unsigned short)r;
}

__device__ __forceinline__ void gl_lds16(const void* g, void* l) {
    __builtin_amdgcn_global_load_lds(
        (const __attribute__((address_space(1))) void*)(uintptr_t)g,
        (__attribute__((address_space(3))) void*)(uintptr_t)l, 16, 0, 0);
}

// ---------------------------------------------------------------------------
// Kernel 1: x (fp32, [b][k] row-major) -> xbT (bf16, k-major 16B units:
// unit g = kc*Bn + b holds x[b][kc*8 .. kc*8+8]).  LDS-transpose per block.
// ---------------------------------------------------------------------------
__global__ __launch_bounds__(256) void prep_x(const float* __restrict__ x,
                                              unsigned short* __restrict__ xbT) {
    __shared__ float t[64][68];          // +4 pad: conflict-free col reads
    const int tid = threadIdx.x;
    const int bb = blockIdx.x >> 2;      // 64 b-tiles of 64
    const int kb = blockIdx.x & 3;       // 4 k-quarters of 64
    const int b0 = bb * 64;
#pragma unroll
    for (int s = 0; s < 4; ++s) {
        const int idx = s * 256 + tid;
        const int r = idx >> 4, c4 = idx & 15;
        const float4 v = *(const float4*)(x + (size_t)(b0 + r) * Dn + kb * 64 + c4 * 4);
        *(float4*)&t[r][c4 * 4] = v;
    }
    __syncthreads();
    const int lane = tid & 63, wv = tid >> 6;
#pragma unroll
    for (int s = 0; s < 2; ++s) {
        const int kcl = s * 4 + wv;      // 0..7 local k-chunk
        us8 u;
#pragma unroll
        for (int q = 0; q < 8; ++q) u[q] = f2bf(t[lane][kcl * 8 + q]);
        *(us8*)(xbT + ((size_t)(kb * 8 + kcl) * Bn + b0 + lane) * 8) = u;
    }
}

// ---------------------------------------------------------------------------
// Fragment extraction, 4-wave version (VERBATIM from the round-4 proven
// kernel): wave wv owns the 64-i strip i = wv*64 + mt*32 + (lane&31).
// Tile slot T is [64][64] fp32 with row-swizzle (r,c)->T[r*64+(c^((r&7)<<2))],
// pre-swizzled at the global source.  af[mt][ks][j] =
//   A[o][i = wv*64 + mt*32 + (lane&31)][k = ks*16 + (lane>>5)*8 + j]
// (32x32x16 A-operand layout, HW-verified round 4, absmax 2.44e-4).
// ---------------------------------------------------------------------------
template <int TI, int TJ>
__device__ __forceinline__ void extract_pair(const float* T, v8bf (&af)[2][16],
                                             const float (&sc2)[2],
                                             int wv, int lane) {
    const int l31 = lane & 31, hw = lane >> 5;
    if (TI == TJ) {
        if (wv == TI) {                  // diagonal tile
#pragma unroll
            for (int mt = 0; mt < 2; ++mt) {
                const int r = mt * 32 + l31;
                const int mr = (r & 7) << 2;
#pragma unroll
                for (int kq = 0; kq < 4; ++kq) {
                    us8 u;
#pragma unroll
                    for (int q = 0; q < 8; ++q) {
                        const int c = kq * 16 + hw * 8 + q;
                        const float v = (r < c) ? T[r * 64 + (c ^ mr)]
                                      : ((r > c) ? T[c * 64 + (r ^ ((c & 7) << 2))]
                                                 : sc2[mt]);
                        u[q] = f2bf(v);
                    }
                    af[mt][TJ * 4 + kq] = __builtin_bit_cast(v8bf, u);
                }
            }
        }
    } else {
        if (wv == TI) {                  // row side: i-block=TI, k-block=TJ
#pragma unroll
            for (int mt = 0; mt < 2; ++mt) {
                const int r = mt * 32 + l31;
                const int mr = (r & 7) << 2;
#pragma unroll
                for (int kq = 0; kq < 4; ++kq) {
                    const int c0 = kq * 16 + hw * 8;
                    const float4 a = *(const float4*)&T[r * 64 + (c0 ^ mr)];
                    const float4 b = *(const float4*)&T[r * 64 + ((c0 + 4) ^ mr)];
                    us8 u;
                    u[0] = f2bf(a.x); u[1] = f2bf(a.y); u[2] = f2bf(a.z); u[3] = f2bf(a.w);
                    u[4] = f2bf(b.x); u[5] = f2bf(b.y); u[6] = f2bf(b.z); u[7] = f2bf(b.w);
                    af[mt][TJ * 4 + kq] = __builtin_bit_cast(v8bf, u);
                }
            }
        } else if (wv == TJ) {           // col side: i-block=TJ, k-block=TI
#pragma unroll
            for (int mt = 0; mt < 2; ++mt) {
                const int cL = mt * 32 + l31;
#pragma unroll
                for (int kq = 0; kq < 4; ++kq) {
                    us8 u;
#pragma unroll
                    for (int q = 0; q < 8; ++q) {
                        const int rL = kq * 16 + hw * 8 + q;
                        u[q] = f2bf(T[rL * 64 + (cL ^ ((rL & 7) << 2))]);
                    }
                    af[mt][TI * 4 + kq] = __builtin_bit_cast(v8bf, u);
                }
            }
        }
    }
}

// Inline-asm waits + compile-scheduler fence (rule #18).
#define WAITV(N)                                              \
    do {                                                      \
        asm volatile("s_waitcnt vmcnt(" #N ")" ::: "memory"); \
        __builtin_amdgcn_sched_barrier(0);                    \
    } while (0)
#define LGKM0()                                               \
    do {                                                      \
        asm volatile("s_waitcnt lgkmcnt(0)" ::: "memory");    \
        __builtin_amdgcn_sched_barrier(0);                    \
    } while (0)
#define BARF()                                                \
    do {                                                      \
        __builtin_amdgcn_sched_barrier(0);                    \
        __builtin_amdgcn_s_barrier();                         \
        __builtin_amdgcn_sched_barrier(0);                    \
    } while (0)

// Stage rot tile (TIv,TJv) into slot DST (16 KB) with source pre-swizzle.
// 256 threads -> 4 gl_lds16 per thread (4 vm-instrs per wave).
#define STAGE_T(TIv, TJv, DST)                                               \
    do {                                                                     \
        const float* s_ = rbase + (TIv) * (64 * Dn) + (TJv) * 64;            \
        _Pragma("unroll")                                                    \
        for (int s = 0; s < 4; ++s) {                                        \
            const int idx = s * 256 + tid;                                   \
            const int r = idx >> 4, c4 = idx & 15;                           \
            gl_lds16(s_ + (size_t)r * Dn + ((c4 ^ (r & 7)) * 4),             \
                     (DST) + idx * 4);                                       \
        }                                                                    \
    } while (0)

// Stage one 32-b X btile into buffer BUF (4 gl_lds16/thread); px auto-advances.
#define STAGE_X(BUF)                                                         \
    do {                                                                     \
        _Pragma("unroll")                                                    \
        for (int s = 0; s < 4; ++s) {                                        \
            gl_lds16(px[s], &Xs[BUF][s * 256 + tid][0]);                     \
            px[s] += 256;  /* next btile: +32 b * 8 shorts */                \
        }                                                                    \
    } while (0)

// ---------------------------------------------------------------------------
// Kernel 2: fused A-build + GEMM + norm + bell.  4-wave blocks, 64-i strips:
// af[2][16] = 128 VGPR per wave -> each xf LDS read feeds TWO MFMAs, halving
// the per-CU LDS-port traffic (R8's binding floor: 16 waves x 16 KB/btile =
// 256 KB ~ 2-3k cyc/CU; now 128 KB ~ 1-1.5k, strictly under the 2048-cyc
// MFMA floor).  Keeps R8's pair schedule (1 barrier / 2 btiles; waves and
// the co-resident block drift -> pipes interleave), group bell-flush every
// 4 btiles, setprio around the MFMA burst, counted-vmcnt staging.
// LDS: 4x16KB Xs + 2 KB ssbuf + 1 KB centL = 67 KB -> 2 blocks/CU,
// 2 waves/SIMD at ~200 VGPR (cap 256 via __launch_bounds__(256,2)).
// ---------------------------------------------------------------------------
__global__ __launch_bounds__(256, 2) void fuzzy_main(
    const float* __restrict__ rots, const float* __restrict__ scales,
    const unsigned short* __restrict__ xbT, const float* __restrict__ cent,
    const float* __restrict__ bvals, float* __restrict__ out) {
    __shared__ __align__(16) unsigned short Xs[4][1024][8];  // 4 x 16 KB
    __shared__ float ssbuf[4][4][32];    // [btile&3][wave][b-local]  2 KB
    __shared__ float centL[Dn];

    const int tid  = threadIdx.x;        // 0..255
    const int lane = tid & 63;
    const int wv   = tid >> 6;           // 0..3: 64-i strip index
    const int l31  = lane & 31, hw = lane >> 5;
    // grid 512 = 8 xcd x 32 olow x 2 bhalf
    const int Lb = blockIdx.x;
    const int o     = (Lb & 7) * 32 + ((Lb >> 3) & 31);
    const int bhalf = Lb >> 8;
    const int bh0   = bhalf * 2048;

    centL[tid] = cent[o * Dn + tid];
    float sc2[2];
#pragma unroll
    for (int mt = 0; mt < 2; ++mt)
        sc2[mt] = scales[o * Dn + wv * 64 + mt * 32 + l31];
    const float bv = bvals[o];

    WAITV(0);   // drain the scalar-ish vector loads -> clean vmcnt counting

    // ---- A-build prologue (VERBATIM round-4 schedule, proven) ----
    float* const S0 = (float*)&Xs[0][0][0];
    float* const S1 = (float*)&Xs[1][0][0];
    float* const S2 = (float*)&Xs[2][0][0];
    float* const S3 = (float*)&Xs[3][0][0];
    const float* const rbase = rots + ((size_t)o << 16);

    v8bf af[2][16];                      // 128 VGPRs

    STAGE_T(0, 1, S0); STAGE_T(2, 3, S1);        // R1 (8 instr/wave)
    STAGE_T(0, 2, S2); STAGE_T(1, 3, S3);        // R2 (16 outstanding)
    WAITV(8); BARF();                            // R1 ready
    extract_pair<0, 1>(S0, af, sc2, wv, lane);   // w0 row, w1 col
    extract_pair<2, 3>(S1, af, sc2, wv, lane);   // w2 row, w3 col
    LGKM0(); BARF();
    STAGE_T(0, 3, S0); STAGE_T(1, 2, S1);        // R3
    WAITV(8); BARF();                            // R2 ready
    extract_pair<0, 2>(S2, af, sc2, wv, lane);
    extract_pair<1, 3>(S3, af, sc2, wv, lane);
    LGKM0(); BARF();
    STAGE_T(0, 0, S2); STAGE_T(1, 1, S3);        // R4
    WAITV(8); BARF();                            // R3 ready
    extract_pair<0, 3>(S0, af, sc2, wv, lane);
    extract_pair<1, 2>(S1, af, sc2, wv, lane);
    LGKM0(); BARF();
    STAGE_T(2, 2, S0); STAGE_T(3, 3, S1);        // R5
    WAITV(8); BARF();                            // R4 ready
    extract_pair<0, 0>(S2, af, sc2, wv, lane);
    extract_pair<1, 1>(S3, af, sc2, wv, lane);
    LGKM0(); BARF();
    WAITV(0); BARF();                            // R5 ready
    extract_pair<2, 2>(S0, af, sc2, wv, lane);
    extract_pair<3, 3>(S1, af, sc2, wv, lane);
    LGKM0(); BARF();                             // all extracts drained

    // ---- X staging pointers: unit (kc local, b local) ----
    const unsigned short* px[4];
#pragma unroll
    for (int s = 0; s < 4; ++s) {
        const int idx = s * 256 + tid;
        px[s] = xbT + ((size_t)(idx >> 5) * Bn + bh0 + (idx & 31)) * 8;
    }

    // prime: btiles 0,1 -> bufs 0,1
    STAGE_X(0); STAGE_X(1);
    WAITV(0); LGKM0(); BARF();

    for (int p = 0; p < 32; ++p) {
        const int t0 = 2 * p;
        // stage next pair into the two bufs NOT read this pair (their
        // previous readers were drained at the last pair-end barrier)
        if (p < 31) { STAGE_X((t0 + 2) & 3); STAGE_X((t0 + 3) & 3); }

#pragma unroll
        for (int s = 0; s < 2; ++s) {
            const int t = t0 + s;
            const int buf = t & 3;

            v16f a0, a1;                 // mt=0 / mt=1 chains (independent)
#pragma unroll
            for (int rg = 0; rg < 16; ++rg) { a0[rg] = 0.f; a1[rg] = 0.f; }
            __builtin_amdgcn_s_setprio(1);
#pragma unroll
            for (int ks = 0; ks < 16; ++ks) {
                const v8bf xf = *(const v8bf*)&Xs[buf][(ks * 2 + hw) * 32 + l31][0];
                a0 = __builtin_amdgcn_mfma_f32_32x32x16_bf16(af[0][ks], xf, a0, 0, 0, 0);
                a1 = __builtin_amdgcn_mfma_f32_32x32x16_bf16(af[1][ks], xf, a1, 0, 0, 0);
            }
            __builtin_amdgcn_s_setprio(0);

            // partial sum_i y^2 over this wave's 64 i.  C/D map (measured
            // m74/m101): b = l31, i_loc = (rg&3)+8*(rg>>2)+4*hw.
            float v = 0.f;
#pragma unroll
            for (int g = 0; g < 4; ++g) {
                const float4 c0 = *(const float4*)&centL[wv * 64 + 8 * g + 4 * hw];
                const float4 c1 = *(const float4*)&centL[wv * 64 + 32 + 8 * g + 4 * hw];
                float y;
                y = a0[g * 4 + 0] + c0.x; v = fmaf(y, y, v);
                y = a0[g * 4 + 1] + c0.y; v = fmaf(y, y, v);
                y = a0[g * 4 + 2] + c0.z; v = fmaf(y, y, v);
                y = a0[g * 4 + 3] + c0.w; v = fmaf(y, y, v);
                y = a1[g * 4 + 0] + c1.x; v = fmaf(y, y, v);
                y = a1[g * 4 + 1] + c1.y; v = fmaf(y, y, v);
                y = a1[g * 4 + 2] + c1.z; v = fmaf(y, y, v);
                y = a1[g * 4 + 3] + c1.w; v = fmaf(y, y, v);
            }
            v += __shfl_xor(v, 32);
            if (lane < 32) ssbuf[t & 3][wv][l31] = v;
        }

        // pair end: stages landed (issued a whole pair ago), LDS drained
        WAITV(0); LGKM0(); BARF();

        // group flush every 2 pairs: btiles 4r..4r+3 complete & visible.
        // Wave wv owns btile 4r+wv (slot wv); lanes 0-31 reduce 4 partials,
        // bell, strided out-write.  Barrier after protects the slots from
        // the next pair's epilogue writes.
        if ((p & 1) == 1) {
            const int tb = (p >> 1) * 4 + wv;
            if (lane < 32) {
                float ssq = ssbuf[wv][0][l31] + ssbuf[wv][1][l31] +
                            ssbuf[wv][2][l31] + ssbuf[wv][3][l31];
                out[(size_t)(bh0 + tb * 32 + l31) * On + o] =
                    1.0f / (1.0f + exp2f(bv * log2f(ssq)));
            }
            LGKM0(); BARF();
        }
    }
}

// ---------------------------------------------------------------------------
// Fallback (only if d_ws is too small): exact fp32, slow but correct.
// ---------------------------------------------------------------------------
__global__ void fallback_kernel(const float* __restrict__ x, const float* __restrict__ scales,
                                const float* __restrict__ rots, const float* __restrict__ cent,
                                const float* __restrict__ bvals, float* __restrict__ out) {
    const int b = blockIdx.x * blockDim.x + threadIdx.x;
    const int o = blockIdx.y;
    if (b >= Bn) return;
    const float* R  = rots + (size_t)o * Dn * Dn;
    const float* xv = x + (size_t)b * Dn;
    float ss = 0.f;
    for (int i = 0; i < Dn; ++i) {
        float a = cent[o * Dn + i];
        for (int j = 0; j < Dn; ++j) {
            const float w = (j > i) ? R[i * Dn + j]
                          : ((j < i) ? R[j * Dn + i] : scales[o * Dn + i]);
            a += w * xv[j];
        }
        ss += a * a;
    }
    out[(size_t)b * On + o] = 1.f / (1.f + powf(ss, bvals[o]));
}

extern "C" void kernel_launch(void* const* d_in, const int* in_sizes, int n_in,
                              void* d_out, int out_size, void* d_ws, size_t ws_size,
                              hipStream_t stream) {
    const float* x         = (const float*)d_in[0];
    const float* scales    = (const float*)d_in[1];
    const float* rots      = (const float*)d_in[2];
    const float* centroids = (const float*)d_in[3];
    const float* bvals     = (const float*)d_in[4];
    float* out = (float*)d_out;

    const size_t needX = (size_t)Bn * Dn * sizeof(unsigned short);      // 2.1 MB

    if (ws_size >= needX) {
        unsigned short* xbT = (unsigned short*)d_ws;
        prep_x<<<dim3(256), 256, 0, stream>>>(x, xbT);
        fuzzy_main<<<dim3(512), 256, 0, stream>>>(rots, scales, xbT, centroids, bvals, out);
    } else {
        fallback_kernel<<<dim3(Bn / 256, On), 256, 0, stream>>>(x, scales, rots, centroids,
                                                                bvals, out);
    }
}